// Round 2
// baseline (301.414 us; speedup 1.0000x reference)
//
#include <hip/hip_runtime.h>
#include <math.h>

#define K1 17
#define SEG_F (K1 * 256)   // 4352 floats per segment-array (permuted: elem d=lane*4+j at j*64+lane)

// workspace float offsets
#define GS_DP 0
#define GS_CF SEG_F
#define GCNT  (2 * SEG_F)          // K1 floats
#define LT    (2 * SEG_F + K1)     // K1 floats (loss_t per segment)
#define LC    (2 * SEG_F + 2 * K1) // K1 floats (loss_cf per segment)
#define ZEROF (2 * SEG_F + 3 * K1) // floats to zero each call
#define MU_DP 9216
#define MU_CF (9216 + SEG_F)

// ---------------- label histogram -> gcnt (float) ----------------
__global__ __launch_bounds__(256) void k_hist(const int4* __restrict__ m4, const int* __restrict__ mask,
                                              float* __restrict__ gcnt, int n4, int nRows)
{
    __shared__ int h[K1];
    if (threadIdx.x < K1) h[threadIdx.x] = 0;
    __syncthreads();
    for (int i = blockIdx.x * 256 + threadIdx.x; i < n4; i += gridDim.x * 256) {
        const int4 m = m4[i];
        atomicAdd(&h[m.x], 1); atomicAdd(&h[m.y], 1);
        atomicAdd(&h[m.z], 1); atomicAdd(&h[m.w], 1);
    }
    if (blockIdx.x == 0) {
        const int tail = nRows & 3;
        if (threadIdx.x < tail) atomicAdd(&h[mask[n4 * 4 + threadIdx.x]], 1);
    }
    __syncthreads();
    if (threadIdx.x < K1) atomicAdd(&gcnt[threadIdx.x], (float)h[threadIdx.x]);
}

// -------- Pass 1 (per feature array): segment sums of row-normalized rows --------
__global__ __launch_bounds__(512) void k_seg(const float4* __restrict__ f, const int* __restrict__ mask,
                                             float* __restrict__ gsum, int nBlocks, int nRows)
{
    __shared__ float s[SEG_F];
    const int tid = threadIdx.x;
    for (int i = tid; i < SEG_F; i += 512) s[i] = 0.0f;
    __syncthreads();

    const int lane = tid & 63;
    const int gw = blockIdx.x * 8 + (tid >> 6);
    const int S = nBlocks * 8;

    float acc[K1][4];
    #pragma unroll
    for (int k = 0; k < K1; ++k) { acc[k][0] = 0; acc[k][1] = 0; acc[k][2] = 0; acc[k][3] = 0; }

    int r = gw;
    for (; r + S < nRows; r += 2 * S) {
        const int l0 = mask[r], l1 = mask[r + S];
        const float4 v0 = f[r * 64 + lane];
        const float4 v1 = f[(r + S) * 64 + lane];
        float s0 = v0.x * v0.x + v0.y * v0.y + v0.z * v0.z + v0.w * v0.w;
        float s1 = v1.x * v1.x + v1.y * v1.y + v1.z * v1.z + v1.w * v1.w;
        #pragma unroll
        for (int o = 32; o > 0; o >>= 1) { s0 += __shfl_xor(s0, o, 64); s1 += __shfl_xor(s1, o, 64); }
        const float i0 = 1.0f / fmaxf(sqrtf(s0), 1e-12f);
        const float i1 = 1.0f / fmaxf(sqrtf(s1), 1e-12f);
        #pragma unroll
        for (int k = 0; k < K1; ++k) {
            const float a0 = (l0 == k) ? i0 : 0.0f;
            const float a1 = (l1 == k) ? i1 : 0.0f;
            acc[k][0] = fmaf(v0.x, a0, acc[k][0]); acc[k][1] = fmaf(v0.y, a0, acc[k][1]);
            acc[k][2] = fmaf(v0.z, a0, acc[k][2]); acc[k][3] = fmaf(v0.w, a0, acc[k][3]);
            acc[k][0] = fmaf(v1.x, a1, acc[k][0]); acc[k][1] = fmaf(v1.y, a1, acc[k][1]);
            acc[k][2] = fmaf(v1.z, a1, acc[k][2]); acc[k][3] = fmaf(v1.w, a1, acc[k][3]);
        }
    }
    for (; r < nRows; r += S) {
        const int l0 = mask[r];
        const float4 v0 = f[r * 64 + lane];
        float s0 = v0.x * v0.x + v0.y * v0.y + v0.z * v0.z + v0.w * v0.w;
        #pragma unroll
        for (int o = 32; o > 0; o >>= 1) s0 += __shfl_xor(s0, o, 64);
        const float i0 = 1.0f / fmaxf(sqrtf(s0), 1e-12f);
        #pragma unroll
        for (int k = 0; k < K1; ++k) {
            const float a0 = (l0 == k) ? i0 : 0.0f;
            acc[k][0] = fmaf(v0.x, a0, acc[k][0]); acc[k][1] = fmaf(v0.y, a0, acc[k][1]);
            acc[k][2] = fmaf(v0.z, a0, acc[k][2]); acc[k][3] = fmaf(v0.w, a0, acc[k][3]);
        }
    }

    // wave -> block LDS (permuted layout: bank = lane%32, 2-way aliasing = free)
    #pragma unroll
    for (int k = 0; k < K1; ++k) {
        atomicAdd(&s[k * 256 + lane],       acc[k][0]);
        atomicAdd(&s[k * 256 + 64 + lane],  acc[k][1]);
        atomicAdd(&s[k * 256 + 128 + lane], acc[k][2]);
        atomicAdd(&s[k * 256 + 192 + lane], acc[k][3]);
    }
    __syncthreads();
    for (int i = tid; i < SEG_F; i += 512) {
        const float v = s[i];
        if (v != 0.0f) atomicAdd(&gsum[i], v);
    }
}

// -------- normalize segment means --------
__global__ __launch_bounds__(256) void k2_mu(float* __restrict__ ws)
{
    const int k = blockIdx.x, t = threadIdx.x;
    const float safe = fmaxf(ws[GCNT + k], 1.0f);
    const float md = ws[GS_DP + k * 256 + t] / safe;
    const float mc = ws[GS_CF + k * 256 + t] / safe;
    float a = md * md, b = mc * mc;
    #pragma unroll
    for (int o = 32; o > 0; o >>= 1) { a += __shfl_xor(a, o, 64); b += __shfl_xor(b, o, 64); }
    __shared__ float A[4], B[4];
    if ((t & 63) == 0) { A[t >> 6] = a; B[t >> 6] = b; }
    __syncthreads();
    const float sa = A[0] + A[1] + A[2] + A[3];
    const float sb = B[0] + B[1] + B[2] + B[3];
    const float id = 1.0f / fmaxf(sqrtf(sa), 1e-12f);
    const float ic = 1.0f / fmaxf(sqrtf(sb), 1e-12f);
    ws[MU_DP + k * 256 + t] = md * id;
    ws[MU_CF + k * 256 + t] = mc * ic;
}

// -------- Pass 2: per-pixel losses -> per-segment sums --------
__global__ __launch_bounds__(512) void k3_loss(
    const float4* __restrict__ dp, const float4* __restrict__ cf,
    const int* __restrict__ mask, float* __restrict__ ws,
    int nBlocks, int nRows)
{
    __shared__ float mud[SEG_F], muc[SEG_F];
    __shared__ float lt[K1], lc[K1];
    const int tid = threadIdx.x;
    for (int i = tid; i < SEG_F; i += 512) {
        mud[i] = ws[MU_DP + i];
        muc[i] = ws[MU_CF + i];
    }
    if (tid < K1) { lt[tid] = 0.0f; lc[tid] = 0.0f; }
    __syncthreads();

    const int lane = tid & 63;
    const int gw = blockIdx.x * 8 + (tid >> 6);
    const int S = nBlocks * 8;

    int r = gw;
    for (; r + S < nRows; r += 2 * S) {
        const int l0 = mask[r], l1 = mask[r + S];
        const float4 v0 = dp[r * 64 + lane],       w0 = cf[r * 64 + lane];
        const float4 v1 = dp[(r + S) * 64 + lane], w1 = cf[(r + S) * 64 + lane];

        float sd0 = v0.x*v0.x + v0.y*v0.y + v0.z*v0.z + v0.w*v0.w;
        float sc0 = w0.x*w0.x + w0.y*w0.y + w0.z*w0.z + w0.w*w0.w;
        float sd1 = v1.x*v1.x + v1.y*v1.y + v1.z*v1.z + v1.w*v1.w;
        float sc1 = w1.x*w1.x + w1.y*w1.y + w1.z*w1.z + w1.w*w1.w;

        const float* md0 = mud + l0 * 256 + lane; const float* md1 = mud + l1 * 256 + lane;
        const float* mc0 = muc + l0 * 256 + lane; const float* mc1 = muc + l1 * 256 + lane;
        const float* bd  = mud + lane;            const float* bc  = muc + lane;

        float dm0 = v0.x*md0[0] + v0.y*md0[64] + v0.z*md0[128] + v0.w*md0[192];
        float db0 = v0.x*bd[0]  + v0.y*bd[64]  + v0.z*bd[128]  + v0.w*bd[192];
        float cm0 = w0.x*mc0[0] + w0.y*mc0[64] + w0.z*mc0[128] + w0.w*mc0[192];
        float cb0 = w0.x*bc[0]  + w0.y*bc[64]  + w0.z*bc[128]  + w0.w*bc[192];
        float dm1 = v1.x*md1[0] + v1.y*md1[64] + v1.z*md1[128] + v1.w*md1[192];
        float db1 = v1.x*bd[0]  + v1.y*bd[64]  + v1.z*bd[128]  + v1.w*bd[192];
        float cm1 = w1.x*mc1[0] + w1.y*mc1[64] + w1.z*mc1[128] + w1.w*mc1[192];
        float cb1 = w1.x*bc[0]  + w1.y*bc[64]  + w1.z*bc[128]  + w1.w*bc[192];

        #pragma unroll
        for (int o = 32; o > 0; o >>= 1) {
            sd0 += __shfl_xor(sd0, o, 64); sc0 += __shfl_xor(sc0, o, 64);
            dm0 += __shfl_xor(dm0, o, 64); db0 += __shfl_xor(db0, o, 64);
            cm0 += __shfl_xor(cm0, o, 64); cb0 += __shfl_xor(cb0, o, 64);
            sd1 += __shfl_xor(sd1, o, 64); sc1 += __shfl_xor(sc1, o, 64);
            dm1 += __shfl_xor(dm1, o, 64); db1 += __shfl_xor(db1, o, 64);
            cm1 += __shfl_xor(cm1, o, 64); cb1 += __shfl_xor(cb1, o, 64);
        }
        if (lane == 0) {
            const float id0 = 1.0f / fmaxf(sqrtf(sd0), 1e-12f);
            const float ic0 = 1.0f / fmaxf(sqrtf(sc0), 1e-12f);
            const float id1 = 1.0f / fmaxf(sqrtf(sd1), 1e-12f);
            const float ic1 = 1.0f / fmaxf(sqrtf(sc1), 1e-12f);
            const float xt0 = (db0 - dm0) * id0 * (1.0f / 0.07f);
            const float xc0 = (cm0 - cb0) * ic0 * (1.0f / 0.07f);
            const float xt1 = (db1 - dm1) * id1 * (1.0f / 0.07f);
            const float xc1 = (cm1 - cb1) * ic1 * (1.0f / 0.07f);
            atomicAdd(&lt[l0], fmaxf(xt0, 0.0f) + log1pf(expf(-fabsf(xt0))));
            atomicAdd(&lc[l0], fmaxf(xc0, 0.0f) + log1pf(expf(-fabsf(xc0))));
            atomicAdd(&lt[l1], fmaxf(xt1, 0.0f) + log1pf(expf(-fabsf(xt1))));
            atomicAdd(&lc[l1], fmaxf(xc1, 0.0f) + log1pf(expf(-fabsf(xc1))));
        }
    }
    for (; r < nRows; r += S) {
        const int l0 = mask[r];
        const float4 v0 = dp[r * 64 + lane], w0 = cf[r * 64 + lane];
        float sd0 = v0.x*v0.x + v0.y*v0.y + v0.z*v0.z + v0.w*v0.w;
        float sc0 = w0.x*w0.x + w0.y*w0.y + w0.z*w0.z + w0.w*w0.w;
        const float* md0 = mud + l0 * 256 + lane;
        const float* mc0 = muc + l0 * 256 + lane;
        const float* bd  = mud + lane; const float* bc = muc + lane;
        float dm0 = v0.x*md0[0] + v0.y*md0[64] + v0.z*md0[128] + v0.w*md0[192];
        float db0 = v0.x*bd[0]  + v0.y*bd[64]  + v0.z*bd[128]  + v0.w*bd[192];
        float cm0 = w0.x*mc0[0] + w0.y*mc0[64] + w0.z*mc0[128] + w0.w*mc0[192];
        float cb0 = w0.x*bc[0]  + w0.y*bc[64]  + w0.z*bc[128]  + w0.w*bc[192];
        #pragma unroll
        for (int o = 32; o > 0; o >>= 1) {
            sd0 += __shfl_xor(sd0, o, 64); sc0 += __shfl_xor(sc0, o, 64);
            dm0 += __shfl_xor(dm0, o, 64); db0 += __shfl_xor(db0, o, 64);
            cm0 += __shfl_xor(cm0, o, 64); cb0 += __shfl_xor(cb0, o, 64);
        }
        if (lane == 0) {
            const float id0 = 1.0f / fmaxf(sqrtf(sd0), 1e-12f);
            const float ic0 = 1.0f / fmaxf(sqrtf(sc0), 1e-12f);
            const float xt0 = (db0 - dm0) * id0 * (1.0f / 0.07f);
            const float xc0 = (cm0 - cb0) * ic0 * (1.0f / 0.07f);
            atomicAdd(&lt[l0], fmaxf(xt0, 0.0f) + log1pf(expf(-fabsf(xt0))));
            atomicAdd(&lc[l0], fmaxf(xc0, 0.0f) + log1pf(expf(-fabsf(xc0))));
        }
    }
    __syncthreads();
    if (tid < K1) {
        atomicAdd(&ws[LT + tid], lt[tid]);
        atomicAdd(&ws[LC + tid], lc[tid]);
    }
}

// -------- finalize scalar --------
__global__ void k4_final(const float* __restrict__ ws, float* __restrict__ out)
{
    const int t = threadIdx.x; // 64
    float vt = 0.0f, vc = 0.0f, nv = 0.0f;
    if (t >= 1 && t < K1) {
        const float cnt = ws[GCNT + t];
        if (cnt >= 3.0f) {
            const float safe = fmaxf(cnt, 1.0f);
            vt = ws[LT + t] / safe;
            vc = ws[LC + t] / safe;
            nv = 1.0f;
        }
    }
    #pragma unroll
    for (int o = 32; o > 0; o >>= 1) {
        vt += __shfl_xor(vt, o, 64);
        vc += __shfl_xor(vc, o, 64);
        nv += __shfl_xor(nv, o, 64);
    }
    if (t == 0) {
        const float n = fmaxf(nv, 1.0f);
        out[0] = vt / n + 0.5f * (vc / n);
    }
}

extern "C" void kernel_launch(void* const* d_in, const int* in_sizes, int n_in,
                              void* d_out, int out_size, void* d_ws, size_t ws_size,
                              hipStream_t stream)
{
    const float4* dp = (const float4*)d_in[0];
    const float4* cf = (const float4*)d_in[1];
    const int* mask  = (const int*)d_in[2];
    float* ws  = (float*)d_ws;
    float* out = (float*)d_out;
    const int nRows = in_sizes[2];

    hipMemsetAsync(ws, 0, ZEROF * sizeof(float), stream);
    k_hist<<<32, 256, 0, stream>>>((const int4*)mask, mask, ws + GCNT, nRows >> 2, nRows);
    const int nB1 = 512;
    k_seg<<<nB1, 512, 0, stream>>>(dp, mask, ws + GS_DP, nB1, nRows);
    k_seg<<<nB1, 512, 0, stream>>>(cf, mask, ws + GS_CF, nB1, nRows);
    k2_mu<<<K1, 256, 0, stream>>>(ws);
    const int nB3 = 1024;
    k3_loss<<<nB3, 512, 0, stream>>>(dp, cf, mask, ws, nB3, nRows);
    k4_final<<<1, 64, 0, stream>>>(ws, out);
}

// Round 3
// 254.364 us; speedup vs baseline: 1.1850x; 1.1850x over previous
//
#include <hip/hip_runtime.h>
#include <math.h>

#define K1 17
#define SEG_F (K1 * 256)          // 4352 floats per segment-array (permuted: elem 4*lane+j at j*64+lane)
#define PART_F (2 * SEG_F + 32)   // per-block partial region (dp sums, cf sums, counts)
#define NGRP 8

// ws float offsets
#define GRED_BASE 0                           // NGRP * 2*SEG_F floats (stage-1 reduce output)
#define MU_BASE   (NGRP * 2 * SEG_F)          // 69632: mu_dp[SEG_F], mu_cf[SEG_F]
#define GCNT_OFF  (MU_BASE + 2 * SEG_F)       // 78336: K1 counts
#define LT_OFF    (GCNT_OFF + K1)             // 78353: K1 loss_t accumulators
#define LC_OFF    (LT_OFF + K1)               // 78370: K1 loss_cf accumulators
#define PART_BASE 78400                       // partial regions start (aligned)

// ---- canonical gfx9 wave64 sum via DPP (VALU-speed, no ds_bpermute) ----
template <int CTRL, int RMASK>
__device__ __forceinline__ float dpp_add(float x) {
    int t = __builtin_amdgcn_update_dpp(0, __float_as_int(x), CTRL, RMASK, 0xf, false);
    return x + __int_as_float(t);
}
__device__ __forceinline__ float wave_sum(float x) {
    x = dpp_add<0x111, 0xf>(x);   // row_shr:1
    x = dpp_add<0x112, 0xf>(x);   // row_shr:2
    x = dpp_add<0x114, 0xf>(x);   // row_shr:4
    x = dpp_add<0x118, 0xf>(x);   // row_shr:8  -> lanes 15/31/47/63 hold row sums
    x = dpp_add<0x142, 0xa>(x);   // row_bcast:15 into rows 1,3
    x = dpp_add<0x143, 0xc>(x);   // row_bcast:31 into rows 2,3 -> lane 63 = total
    return __int_as_float(__builtin_amdgcn_readlane(__float_as_int(x), 63)); // broadcast
}
__device__ __forceinline__ float dot4s(const float4 v) {
    return v.x * v.x + v.y * v.y + v.z * v.z + v.w * v.w;
}

// ---- Pass 1: row-normalize both arrays, segment-sum into LDS, write block partials ----
__global__ __launch_bounds__(1024) void kA(const float4* __restrict__ dp, const float4* __restrict__ cf,
                                           const int* __restrict__ mask, float* __restrict__ part,
                                           int nPart, int nRows)
{
    __shared__ float s[2 * SEG_F];
    __shared__ int hist[K1];
    const int tid = threadIdx.x;
    for (int i = tid; i < 2 * SEG_F; i += 1024) s[i] = 0.0f;
    if (tid < K1) hist[tid] = 0;
    __syncthreads();

    const int lane = tid & 63;
    const int gw = blockIdx.x * 16 + (tid >> 6);
    const int S = nPart * 16;

    int r = gw;
    for (; r + S < nRows; r += 2 * S) {
        const int l0 = mask[r], l1 = mask[r + S];
        const float4 v0 = dp[(size_t)r * 64 + lane];
        const float4 w0 = cf[(size_t)r * 64 + lane];
        const float4 v1 = dp[(size_t)(r + S) * 64 + lane];
        const float4 w1 = cf[(size_t)(r + S) * 64 + lane];
        const float nd0 = wave_sum(dot4s(v0));
        const float nc0 = wave_sum(dot4s(w0));
        const float nd1 = wave_sum(dot4s(v1));
        const float nc1 = wave_sum(dot4s(w1));
        const float id0 = 1.0f / fmaxf(sqrtf(nd0), 1e-12f);
        const float ic0 = 1.0f / fmaxf(sqrtf(nc0), 1e-12f);
        const float id1 = 1.0f / fmaxf(sqrtf(nd1), 1e-12f);
        const float ic1 = 1.0f / fmaxf(sqrtf(nc1), 1e-12f);
        float* a0 = s + l0 * 256 + lane;           // banks lane%32, 2 lanes/bank distinct addr = free
        atomicAdd(a0,       v0.x * id0); atomicAdd(a0 + 64,  v0.y * id0);
        atomicAdd(a0 + 128, v0.z * id0); atomicAdd(a0 + 192, v0.w * id0);
        float* b0 = a0 + SEG_F;
        atomicAdd(b0,       w0.x * ic0); atomicAdd(b0 + 64,  w0.y * ic0);
        atomicAdd(b0 + 128, w0.z * ic0); atomicAdd(b0 + 192, w0.w * ic0);
        float* a1 = s + l1 * 256 + lane;
        atomicAdd(a1,       v1.x * id1); atomicAdd(a1 + 64,  v1.y * id1);
        atomicAdd(a1 + 128, v1.z * id1); atomicAdd(a1 + 192, v1.w * id1);
        float* b1 = a1 + SEG_F;
        atomicAdd(b1,       w1.x * ic1); atomicAdd(b1 + 64,  w1.y * ic1);
        atomicAdd(b1 + 128, w1.z * ic1); atomicAdd(b1 + 192, w1.w * ic1);
        if (lane == 0) { atomicAdd(&hist[l0], 1); atomicAdd(&hist[l1], 1); }
    }
    for (; r < nRows; r += S) {
        const int l0 = mask[r];
        const float4 v0 = dp[(size_t)r * 64 + lane];
        const float4 w0 = cf[(size_t)r * 64 + lane];
        const float nd0 = wave_sum(dot4s(v0));
        const float nc0 = wave_sum(dot4s(w0));
        const float id0 = 1.0f / fmaxf(sqrtf(nd0), 1e-12f);
        const float ic0 = 1.0f / fmaxf(sqrtf(nc0), 1e-12f);
        float* a0 = s + l0 * 256 + lane;
        atomicAdd(a0,       v0.x * id0); atomicAdd(a0 + 64,  v0.y * id0);
        atomicAdd(a0 + 128, v0.z * id0); atomicAdd(a0 + 192, v0.w * id0);
        float* b0 = a0 + SEG_F;
        atomicAdd(b0,       w0.x * ic0); atomicAdd(b0 + 64,  w0.y * ic0);
        atomicAdd(b0 + 128, w0.z * ic0); atomicAdd(b0 + 192, w0.w * ic0);
        if (lane == 0) atomicAdd(&hist[l0], 1);
    }
    __syncthreads();
    float* outp = part + (size_t)blockIdx.x * PART_F;
    for (int i = tid; i < 2 * SEG_F; i += 1024) outp[i] = s[i];
    if (tid < K1) outp[2 * SEG_F + tid] = (float)hist[tid];
}

// ---- stage-1 reduce of partials: [nPart][8704] -> [NGRP][8704], full-GPU spread ----
__global__ __launch_bounds__(256) void kRed(const float* __restrict__ part, float* __restrict__ gred, int nPart)
{
    const int col = blockIdx.x * 256 + threadIdx.x;   // 0..8703 (34 blocks)
    const int g = blockIdx.y;                          // 0..NGRP-1
    const int per = nPart / NGRP;
    const float* p = part + (size_t)g * per * PART_F + col;
    float acc = 0.0f;
    for (int b = 0; b < per; ++b) acc += p[(size_t)b * PART_F];
    gred[g * (2 * SEG_F) + col] = acc;
}

// ---- stage-2: finish sums, normalize means ----
__global__ __launch_bounds__(256) void k_mu(float* __restrict__ ws, int nPart)
{
    const int k = blockIdx.x, t = threadIdx.x;
    __shared__ float C[256];
    float c = 0.0f;
    for (int b = t; b < nPart; b += 256) c += ws[PART_BASE + (size_t)b * PART_F + 2 * SEG_F + k];
    C[t] = c; __syncthreads();
    for (int s2 = 128; s2 > 0; s2 >>= 1) { if (t < s2) C[t] += C[t + s2]; __syncthreads(); }
    const float cnt = C[0];
    const float safe = fmaxf(cnt, 1.0f);
    float sd = 0.0f, sc = 0.0f;
    #pragma unroll
    for (int g = 0; g < NGRP; ++g) {
        sd += ws[GRED_BASE + g * 2 * SEG_F + k * 256 + t];
        sc += ws[GRED_BASE + g * 2 * SEG_F + SEG_F + k * 256 + t];
    }
    const float md = sd / safe, mc = sc / safe;
    __shared__ float A[256], B[256];
    A[t] = md * md; B[t] = mc * mc;
    __syncthreads();
    for (int s2 = 128; s2 > 0; s2 >>= 1) { if (t < s2) { A[t] += A[t + s2]; B[t] += B[t + s2]; } __syncthreads(); }
    const float id = 1.0f / fmaxf(sqrtf(A[0]), 1e-12f);
    const float ic = 1.0f / fmaxf(sqrtf(B[0]), 1e-12f);
    ws[MU_BASE + k * 256 + t]         = md * id;
    ws[MU_BASE + SEG_F + k * 256 + t] = mc * ic;
    if (t == 0) ws[GCNT_OFF + k] = cnt;
}

// ---- Pass 2: per-pixel losses -> per-segment sums ----
__global__ __launch_bounds__(256) void k_loss(const float4* __restrict__ dp, const float4* __restrict__ cf,
                                              const int* __restrict__ mask, float* __restrict__ ws,
                                              int nBlocks, int nRows)
{
    __shared__ float mud[SEG_F], muc[SEG_F];
    __shared__ float lt[K1], lc[K1];
    const int tid = threadIdx.x;
    for (int i = tid; i < SEG_F; i += 256) { mud[i] = ws[MU_BASE + i]; muc[i] = ws[MU_BASE + SEG_F + i]; }
    if (tid < K1) { lt[tid] = 0.0f; lc[tid] = 0.0f; }
    __syncthreads();

    const int lane = tid & 63;
    const int gw = blockIdx.x * 4 + (tid >> 6);
    const int S = nBlocks * 4;

    for (int r = gw; r < nRows; r += S) {
        const int l0 = mask[r];
        const float4 v0 = dp[(size_t)r * 64 + lane];
        const float4 w0 = cf[(size_t)r * 64 + lane];
        const float* md_ = mud + l0 * 256 + lane;
        const float* mc_ = muc + l0 * 256 + lane;
        const float* bd  = mud + lane;
        const float* bc  = muc + lane;
        const float nd = wave_sum(dot4s(v0));
        const float nc = wave_sum(dot4s(w0));
        const float dm = wave_sum(v0.x * md_[0] + v0.y * md_[64] + v0.z * md_[128] + v0.w * md_[192]);
        const float db = wave_sum(v0.x * bd[0]  + v0.y * bd[64]  + v0.z * bd[128]  + v0.w * bd[192]);
        const float cm = wave_sum(w0.x * mc_[0] + w0.y * mc_[64] + w0.z * mc_[128] + w0.w * mc_[192]);
        const float cb = wave_sum(w0.x * bc[0]  + w0.y * bc[64]  + w0.z * bc[128]  + w0.w * bc[192]);
        // all lanes hold uniform sums; compute softplus uniformly, lane 0 commits
        const float id0 = 1.0f / fmaxf(sqrtf(nd), 1e-12f);
        const float ic0 = 1.0f / fmaxf(sqrtf(nc), 1e-12f);
        const float xt = (db - dm) * id0 * (1.0f / 0.07f);
        const float xc = (cm - cb) * ic0 * (1.0f / 0.07f);
        const float plt = fmaxf(xt, 0.0f) + log1pf(expf(-fabsf(xt)));
        const float plc = fmaxf(xc, 0.0f) + log1pf(expf(-fabsf(xc)));
        if (lane == 0) { atomicAdd(&lt[l0], plt); atomicAdd(&lc[l0], plc); }
    }
    __syncthreads();
    if (tid < K1) {
        atomicAdd(&ws[LT_OFF + tid], lt[tid]);
        atomicAdd(&ws[LC_OFF + tid], lc[tid]);
    }
}

// ---- finalize scalar ----
__global__ void k_final(const float* __restrict__ ws, float* __restrict__ out)
{
    const int t = threadIdx.x; // 64
    float vt = 0.0f, vc = 0.0f, nv = 0.0f;
    if (t >= 1 && t < K1) {
        const float cnt = ws[GCNT_OFF + t];
        if (cnt >= 3.0f) {  // MIN_PIXELS
            const float safe = fmaxf(cnt, 1.0f);
            vt = ws[LT_OFF + t] / safe;
            vc = ws[LC_OFF + t] / safe;
            nv = 1.0f;
        }
    }
    #pragma unroll
    for (int o = 32; o > 0; o >>= 1) {
        vt += __shfl_xor(vt, o, 64);
        vc += __shfl_xor(vc, o, 64);
        nv += __shfl_xor(nv, o, 64);
    }
    if (t == 0) {
        const float n = fmaxf(nv, 1.0f);
        out[0] = vt / n + 0.5f * (vc / n);  // LAMBDA_CF = 0.5
    }
}

extern "C" void kernel_launch(void* const* d_in, const int* in_sizes, int n_in,
                              void* d_out, int out_size, void* d_ws, size_t ws_size,
                              hipStream_t stream)
{
    const float4* dp = (const float4*)d_in[0];
    const float4* cf = (const float4*)d_in[1];
    const int* mask  = (const int*)d_in[2];
    float* ws  = (float*)d_ws;
    float* out = (float*)d_out;
    const int nRows = in_sizes[2];

    long availF = (long)(ws_size / 4) - PART_BASE;
    int nPart = (int)(availF / PART_F);
    if (nPart > 256) nPart = 256;
    nPart &= ~7;            // multiple of NGRP
    if (nPart < 8) nPart = 8;

    hipMemsetAsync((void*)(ws + LT_OFF), 0, 2 * K1 * sizeof(float), stream);
    kA<<<nPart, 1024, 0, stream>>>(dp, cf, mask, ws + PART_BASE, nPart, nRows);
    kRed<<<dim3(34, NGRP), 256, 0, stream>>>(ws + PART_BASE, ws + GRED_BASE, nPart);
    k_mu<<<K1, 256, 0, stream>>>(ws, nPart);
    const int nB3 = 1024;
    k_loss<<<nB3, 256, 0, stream>>>(dp, cf, mask, ws, nB3, nRows);
    k_final<<<1, 64, 0, stream>>>(ws, out);
}

// Round 4
// 110.246 us; speedup vs baseline: 2.7340x; 2.3073x over previous
//
#include <hip/hip_runtime.h>
#include <math.h>

#define K1 17
#define SEG_F (K1 * 256)          // 4352 elems per segment-array (permuted: elem 4*lane+j at j*64+lane)
#define PART_F (2 * SEG_F + 32)   // per-block partial region (dp sums, cf sums, counts) in floats
#define NGRP 8

#define SCALE_SUM 65536.0f
#define INV_SUM   (1.0f / 65536.0f)
#define SCALE_L   8192.0f
#define INV_L     (1.0f / 8192.0f)

// ws offsets in 4-byte units
#define GRED_BASE 0                           // NGRP * 2*SEG_F floats
#define MU_BASE   (NGRP * 2 * SEG_F)          // 69632: mu_dp[SEG_F], mu_cf[SEG_F]
#define GCNT_OFF  (MU_BASE + 2 * SEG_F)       // 78336: K1 floats
#define LT_OFF    (GCNT_OFF + K1)             // 78353: K1 int accumulators
#define LC_OFF    (LT_OFF + K1)               // 78370: K1 int accumulators
#define PART_BASE 78400

// ---- wave64 sum via DPP (VALU-speed) ----
template <int CTRL, int RMASK>
__device__ __forceinline__ float dpp_add(float x) {
    int t = __builtin_amdgcn_update_dpp(0, __float_as_int(x), CTRL, RMASK, 0xf, false);
    return x + __int_as_float(t);
}
__device__ __forceinline__ float wave_sum(float x) {
    x = dpp_add<0x111, 0xf>(x);
    x = dpp_add<0x112, 0xf>(x);
    x = dpp_add<0x114, 0xf>(x);
    x = dpp_add<0x118, 0xf>(x);
    x = dpp_add<0x142, 0xa>(x);
    x = dpp_add<0x143, 0xc>(x);
    return __int_as_float(__builtin_amdgcn_readlane(__float_as_int(x), 63));
}
__device__ __forceinline__ float dot4s(const float4 v) {
    return v.x * v.x + v.y * v.y + v.z * v.z + v.w * v.w;
}

// ---- Pass 1: row-normalize both arrays, fixed-point segment-sum in LDS, write float partials ----
__global__ __launch_bounds__(1024) void kA(const float4* __restrict__ dp, const float4* __restrict__ cf,
                                           const int* __restrict__ mask, float* __restrict__ part,
                                           int nPart, int nRows)
{
    __shared__ int s[2 * SEG_F];
    __shared__ int hist[K1];
    const int tid = threadIdx.x;
    for (int i = tid; i < 2 * SEG_F; i += 1024) s[i] = 0;
    if (tid < K1) hist[tid] = 0;
    __syncthreads();

    const int lane = tid & 63;
    const int gw = blockIdx.x * 16 + (tid >> 6);
    const int S = nPart * 16;

    int r = gw;
    for (; r + S < nRows; r += 2 * S) {
        const int l0 = mask[r], l1 = mask[r + S];
        const float4 v0 = dp[(size_t)r * 64 + lane];
        const float4 w0 = cf[(size_t)r * 64 + lane];
        const float4 v1 = dp[(size_t)(r + S) * 64 + lane];
        const float4 w1 = cf[(size_t)(r + S) * 64 + lane];
        const float nd0 = wave_sum(dot4s(v0));
        const float nc0 = wave_sum(dot4s(w0));
        const float nd1 = wave_sum(dot4s(v1));
        const float nc1 = wave_sum(dot4s(w1));
        const float f0 = SCALE_SUM / fmaxf(sqrtf(nd0), 1e-12f);
        const float g0 = SCALE_SUM / fmaxf(sqrtf(nc0), 1e-12f);
        const float f1 = SCALE_SUM / fmaxf(sqrtf(nd1), 1e-12f);
        const float g1 = SCALE_SUM / fmaxf(sqrtf(nc1), 1e-12f);
        int* a0 = s + l0 * 256 + lane;   // banks lane%32, 2 lanes/bank distinct addr = free
        atomicAdd(a0,       __float2int_rn(v0.x * f0));
        atomicAdd(a0 + 64,  __float2int_rn(v0.y * f0));
        atomicAdd(a0 + 128, __float2int_rn(v0.z * f0));
        atomicAdd(a0 + 192, __float2int_rn(v0.w * f0));
        int* b0 = a0 + SEG_F;
        atomicAdd(b0,       __float2int_rn(w0.x * g0));
        atomicAdd(b0 + 64,  __float2int_rn(w0.y * g0));
        atomicAdd(b0 + 128, __float2int_rn(w0.z * g0));
        atomicAdd(b0 + 192, __float2int_rn(w0.w * g0));
        int* a1 = s + l1 * 256 + lane;
        atomicAdd(a1,       __float2int_rn(v1.x * f1));
        atomicAdd(a1 + 64,  __float2int_rn(v1.y * f1));
        atomicAdd(a1 + 128, __float2int_rn(v1.z * f1));
        atomicAdd(a1 + 192, __float2int_rn(v1.w * f1));
        int* b1 = a1 + SEG_F;
        atomicAdd(b1,       __float2int_rn(w1.x * g1));
        atomicAdd(b1 + 64,  __float2int_rn(w1.y * g1));
        atomicAdd(b1 + 128, __float2int_rn(w1.z * g1));
        atomicAdd(b1 + 192, __float2int_rn(w1.w * g1));
        if (lane == 0) { atomicAdd(&hist[l0], 1); atomicAdd(&hist[l1], 1); }
    }
    for (; r < nRows; r += S) {
        const int l0 = mask[r];
        const float4 v0 = dp[(size_t)r * 64 + lane];
        const float4 w0 = cf[(size_t)r * 64 + lane];
        const float nd0 = wave_sum(dot4s(v0));
        const float nc0 = wave_sum(dot4s(w0));
        const float f0 = SCALE_SUM / fmaxf(sqrtf(nd0), 1e-12f);
        const float g0 = SCALE_SUM / fmaxf(sqrtf(nc0), 1e-12f);
        int* a0 = s + l0 * 256 + lane;
        atomicAdd(a0,       __float2int_rn(v0.x * f0));
        atomicAdd(a0 + 64,  __float2int_rn(v0.y * f0));
        atomicAdd(a0 + 128, __float2int_rn(v0.z * f0));
        atomicAdd(a0 + 192, __float2int_rn(v0.w * f0));
        int* b0 = a0 + SEG_F;
        atomicAdd(b0,       __float2int_rn(w0.x * g0));
        atomicAdd(b0 + 64,  __float2int_rn(w0.y * g0));
        atomicAdd(b0 + 128, __float2int_rn(w0.z * g0));
        atomicAdd(b0 + 192, __float2int_rn(w0.w * g0));
        if (lane == 0) atomicAdd(&hist[l0], 1);
    }
    __syncthreads();
    float* outp = part + (size_t)blockIdx.x * PART_F;
    for (int i = tid; i < 2 * SEG_F; i += 1024) outp[i] = (float)s[i] * INV_SUM;
    if (tid < K1) outp[2 * SEG_F + tid] = (float)hist[tid];
}

// ---- stage-1 reduce of partials: [nPart][PART_F] -> [NGRP][2*SEG_F] ----
__global__ __launch_bounds__(256) void kRed(const float* __restrict__ part, float* __restrict__ gred, int nPart)
{
    const int col = blockIdx.x * 256 + threadIdx.x;   // 0..8703 (34 blocks)
    const int g = blockIdx.y;
    const int per = nPart / NGRP;
    const float* p = part + (size_t)g * per * PART_F + col;
    float acc = 0.0f;
    for (int b = 0; b < per; ++b) acc += p[(size_t)b * PART_F];
    gred[g * (2 * SEG_F) + col] = acc;
}

// ---- stage-2: finish sums, normalize means ----
__global__ __launch_bounds__(256) void k_mu(float* __restrict__ ws, int nPart)
{
    const int k = blockIdx.x, t = threadIdx.x;
    __shared__ float C[256];
    float c = 0.0f;
    for (int b = t; b < nPart; b += 256) c += ws[PART_BASE + (size_t)b * PART_F + 2 * SEG_F + k];
    C[t] = c; __syncthreads();
    for (int s2 = 128; s2 > 0; s2 >>= 1) { if (t < s2) C[t] += C[t + s2]; __syncthreads(); }
    const float cnt = C[0];
    const float safe = fmaxf(cnt, 1.0f);
    float sd = 0.0f, sc = 0.0f;
    #pragma unroll
    for (int g = 0; g < NGRP; ++g) {
        sd += ws[GRED_BASE + g * 2 * SEG_F + k * 256 + t];
        sc += ws[GRED_BASE + g * 2 * SEG_F + SEG_F + k * 256 + t];
    }
    const float md = sd / safe, mc = sc / safe;
    __shared__ float A[256], B[256];
    A[t] = md * md; B[t] = mc * mc;
    __syncthreads();
    for (int s2 = 128; s2 > 0; s2 >>= 1) { if (t < s2) { A[t] += A[t + s2]; B[t] += B[t + s2]; } __syncthreads(); }
    const float id = 1.0f / fmaxf(sqrtf(A[0]), 1e-12f);
    const float ic = 1.0f / fmaxf(sqrtf(B[0]), 1e-12f);
    ws[MU_BASE + k * 256 + t]         = md * id;
    ws[MU_BASE + SEG_F + k * 256 + t] = mc * ic;
    if (t == 0) ws[GCNT_OFF + k] = cnt;
}

// ---- Pass 2: per-pixel losses -> fixed-point per-segment sums ----
__global__ __launch_bounds__(512) void k_loss(const float4* __restrict__ dp, const float4* __restrict__ cf,
                                              const int* __restrict__ mask, float* __restrict__ ws,
                                              int nBlocks, int nRows)
{
    __shared__ float mud[SEG_F], muc[SEG_F];
    __shared__ int lt[K1], lc[K1];
    const int tid = threadIdx.x;
    for (int i = tid; i < SEG_F; i += 512) { mud[i] = ws[MU_BASE + i]; muc[i] = ws[MU_BASE + SEG_F + i]; }
    if (tid < K1) { lt[tid] = 0; lc[tid] = 0; }
    __syncthreads();

    const int lane = tid & 63;
    const int gw = blockIdx.x * 8 + (tid >> 6);
    const int S = nBlocks * 8;

    for (int r = gw; r < nRows; r += S) {
        const int l0 = mask[r];
        const float4 v0 = dp[(size_t)r * 64 + lane];
        const float4 w0 = cf[(size_t)r * 64 + lane];
        const float* md_ = mud + l0 * 256 + lane;
        const float* mc_ = muc + l0 * 256 + lane;
        const float* bd  = mud + lane;
        const float* bc  = muc + lane;
        const float nd = wave_sum(dot4s(v0));
        const float nc = wave_sum(dot4s(w0));
        const float dm = wave_sum(v0.x * md_[0] + v0.y * md_[64] + v0.z * md_[128] + v0.w * md_[192]);
        const float db = wave_sum(v0.x * bd[0]  + v0.y * bd[64]  + v0.z * bd[128]  + v0.w * bd[192]);
        const float cm = wave_sum(w0.x * mc_[0] + w0.y * mc_[64] + w0.z * mc_[128] + w0.w * mc_[192]);
        const float cb = wave_sum(w0.x * bc[0]  + w0.y * bc[64]  + w0.z * bc[128]  + w0.w * bc[192]);
        const float id0 = 1.0f / fmaxf(sqrtf(nd), 1e-12f);
        const float ic0 = 1.0f / fmaxf(sqrtf(nc), 1e-12f);
        const float xt = (db - dm) * id0 * (1.0f / 0.07f);
        const float xc = (cm - cb) * ic0 * (1.0f / 0.07f);
        const float plt = fmaxf(xt, 0.0f) + log1pf(expf(-fabsf(xt)));
        const float plc = fmaxf(xc, 0.0f) + log1pf(expf(-fabsf(xc)));
        if (lane == 0) {
            atomicAdd(&lt[l0], __float2int_rn(plt * SCALE_L));
            atomicAdd(&lc[l0], __float2int_rn(plc * SCALE_L));
        }
    }
    __syncthreads();
    if (tid < K1) {
        int* LT = (int*)ws + LT_OFF;
        int* LC = (int*)ws + LC_OFF;
        atomicAdd(&LT[tid], lt[tid]);
        atomicAdd(&LC[tid], lc[tid]);
    }
}

// ---- finalize scalar ----
__global__ void k_final(const float* __restrict__ ws, float* __restrict__ out)
{
    const int t = threadIdx.x; // 64
    const int* LT = (const int*)ws + LT_OFF;
    const int* LC = (const int*)ws + LC_OFF;
    float vt = 0.0f, vc = 0.0f, nv = 0.0f;
    if (t >= 1 && t < K1) {
        const float cnt = ws[GCNT_OFF + t];
        if (cnt >= 3.0f) {  // MIN_PIXELS
            const float safe = fmaxf(cnt, 1.0f);
            vt = (float)LT[t] * INV_L / safe;
            vc = (float)LC[t] * INV_L / safe;
            nv = 1.0f;
        }
    }
    #pragma unroll
    for (int o = 32; o > 0; o >>= 1) {
        vt += __shfl_xor(vt, o, 64);
        vc += __shfl_xor(vc, o, 64);
        nv += __shfl_xor(nv, o, 64);
    }
    if (t == 0) {
        const float n = fmaxf(nv, 1.0f);
        out[0] = vt / n + 0.5f * (vc / n);  // LAMBDA_CF = 0.5
    }
}

extern "C" void kernel_launch(void* const* d_in, const int* in_sizes, int n_in,
                              void* d_out, int out_size, void* d_ws, size_t ws_size,
                              hipStream_t stream)
{
    const float4* dp = (const float4*)d_in[0];
    const float4* cf = (const float4*)d_in[1];
    const int* mask  = (const int*)d_in[2];
    float* ws  = (float*)d_ws;
    float* out = (float*)d_out;
    const int nRows = in_sizes[2];

    long availF = (long)(ws_size / 4) - PART_BASE;
    int nPart = (int)(availF / PART_F);
    if (nPart > 512) nPart = 512;
    nPart &= ~7;            // multiple of NGRP
    if (nPart < 8) nPart = 8;

    hipMemsetAsync((void*)(ws + LT_OFF), 0, 2 * K1 * sizeof(int), stream);
    kA<<<nPart, 1024, 0, stream>>>(dp, cf, mask, ws + PART_BASE, nPart, nRows);
    kRed<<<dim3(34, NGRP), 256, 0, stream>>>(ws + PART_BASE, ws + GRED_BASE, nPart);
    k_mu<<<K1, 256, 0, stream>>>(ws, nPart);
    const int nB3 = 1024;
    k_loss<<<nB3, 512, 0, stream>>>(dp, cf, mask, ws, nB3, nRows);
    k_final<<<1, 64, 0, stream>>>(ws, out);
}

// Round 5
// 98.787 us; speedup vs baseline: 3.0512x; 1.1160x over previous
//
#include <hip/hip_runtime.h>
#include <math.h>

#define K1 17
#define SEG_F (K1 * 256)          // 4352 elems per segment-array (permuted: elem 4*lane+j at j*64+lane)
#define PART_F (2 * SEG_F + 32)   // per-block partial region (dp sums, cf sums, counts) in floats
#define NGRP 8

#define SCALE_SUM 65536.0f
#define INV_SUM   (1.0f / 65536.0f)
#define SCALE_L   8192.0f
#define INV_L     (1.0f / 8192.0f)

// ws offsets in 4-byte units
#define GRED_BASE 0                           // NGRP * 2*SEG_F floats
#define MU_BASE   (NGRP * 2 * SEG_F)          // 69632: mu_dp[SEG_F], mu_cf[SEG_F] (NATURAL layout)
#define GCNT_OFF  (MU_BASE + 2 * SEG_F)       // 78336: K1 floats
#define LT_OFF    (GCNT_OFF + K1)             // K1 int accumulators
#define LC_OFF    (LT_OFF + K1)               // K1 int accumulators
#define PART_BASE 78400

// ---- wave64 sum via DPP (VALU-speed) ----
template <int CTRL, int RMASK>
__device__ __forceinline__ float dpp_add(float x) {
    int t = __builtin_amdgcn_update_dpp(0, __float_as_int(x), CTRL, RMASK, 0xf, false);
    return x + __int_as_float(t);
}
__device__ __forceinline__ float wave_sum(float x) {
    x = dpp_add<0x111, 0xf>(x);
    x = dpp_add<0x112, 0xf>(x);
    x = dpp_add<0x114, 0xf>(x);
    x = dpp_add<0x118, 0xf>(x);
    x = dpp_add<0x142, 0xa>(x);
    x = dpp_add<0x143, 0xc>(x);
    return __int_as_float(__builtin_amdgcn_readlane(__float_as_int(x), 63));
}
__device__ __forceinline__ float dot4s(const float4 v) {
    return v.x * v.x + v.y * v.y + v.z * v.z + v.w * v.w;
}
// softplus(x) = max(x,0) + ln(1+exp(-|x|)) via native v_exp/v_log (log2-based)
__device__ __forceinline__ float softplus_f(float x) {
    const float a = -fabsf(x) * 1.4426950408889634f;
    float e; asm("v_exp_f32 %0, %1" : "=v"(e) : "v"(a));
    float l; asm("v_log_f32 %0, %1" : "=v"(l) : "v"(1.0f + e));
    return fmaxf(x, 0.0f) + l * 0.6931471805599453f;
}

// ---- Pass 1: row-normalize both arrays, fixed-point segment-sum in LDS, write float partials ----
__global__ __launch_bounds__(1024) void kA(const float4* __restrict__ dp, const float4* __restrict__ cf,
                                           const int* __restrict__ mask, float* __restrict__ part,
                                           int nPart, int nRows)
{
    __shared__ int s[2 * SEG_F];
    __shared__ int hist[K1];
    const int tid = threadIdx.x;
    for (int i = tid; i < 2 * SEG_F; i += 1024) s[i] = 0;
    if (tid < K1) hist[tid] = 0;
    __syncthreads();

    const int lane = tid & 63;
    const int gw = blockIdx.x * 16 + (tid >> 6);
    const int S = nPart * 16;

    int r = gw;
    for (; r + S < nRows; r += 2 * S) {
        const int l0 = mask[r], l1 = mask[r + S];
        const float4 v0 = dp[(size_t)r * 64 + lane];
        const float4 w0 = cf[(size_t)r * 64 + lane];
        const float4 v1 = dp[(size_t)(r + S) * 64 + lane];
        const float4 w1 = cf[(size_t)(r + S) * 64 + lane];
        const float nd0 = wave_sum(dot4s(v0));
        const float nc0 = wave_sum(dot4s(w0));
        const float nd1 = wave_sum(dot4s(v1));
        const float nc1 = wave_sum(dot4s(w1));
        const float f0 = SCALE_SUM / fmaxf(sqrtf(nd0), 1e-12f);
        const float g0 = SCALE_SUM / fmaxf(sqrtf(nc0), 1e-12f);
        const float f1 = SCALE_SUM / fmaxf(sqrtf(nd1), 1e-12f);
        const float g1 = SCALE_SUM / fmaxf(sqrtf(nc1), 1e-12f);
        int* a0 = s + l0 * 256 + lane;   // banks lane%32, 2 lanes/bank distinct addr = free
        atomicAdd(a0,       (int)(v0.x * f0));
        atomicAdd(a0 + 64,  (int)(v0.y * f0));
        atomicAdd(a0 + 128, (int)(v0.z * f0));
        atomicAdd(a0 + 192, (int)(v0.w * f0));
        int* b0 = a0 + SEG_F;
        atomicAdd(b0,       (int)(w0.x * g0));
        atomicAdd(b0 + 64,  (int)(w0.y * g0));
        atomicAdd(b0 + 128, (int)(w0.z * g0));
        atomicAdd(b0 + 192, (int)(w0.w * g0));
        int* a1 = s + l1 * 256 + lane;
        atomicAdd(a1,       (int)(v1.x * f1));
        atomicAdd(a1 + 64,  (int)(v1.y * f1));
        atomicAdd(a1 + 128, (int)(v1.z * f1));
        atomicAdd(a1 + 192, (int)(v1.w * f1));
        int* b1 = a1 + SEG_F;
        atomicAdd(b1,       (int)(w1.x * g1));
        atomicAdd(b1 + 64,  (int)(w1.y * g1));
        atomicAdd(b1 + 128, (int)(w1.z * g1));
        atomicAdd(b1 + 192, (int)(w1.w * g1));
        if (lane == 0) { atomicAdd(&hist[l0], 1); atomicAdd(&hist[l1], 1); }
    }
    for (; r < nRows; r += S) {
        const int l0 = mask[r];
        const float4 v0 = dp[(size_t)r * 64 + lane];
        const float4 w0 = cf[(size_t)r * 64 + lane];
        const float nd0 = wave_sum(dot4s(v0));
        const float nc0 = wave_sum(dot4s(w0));
        const float f0 = SCALE_SUM / fmaxf(sqrtf(nd0), 1e-12f);
        const float g0 = SCALE_SUM / fmaxf(sqrtf(nc0), 1e-12f);
        int* a0 = s + l0 * 256 + lane;
        atomicAdd(a0,       (int)(v0.x * f0));
        atomicAdd(a0 + 64,  (int)(v0.y * f0));
        atomicAdd(a0 + 128, (int)(v0.z * f0));
        atomicAdd(a0 + 192, (int)(v0.w * f0));
        int* b0 = a0 + SEG_F;
        atomicAdd(b0,       (int)(w0.x * g0));
        atomicAdd(b0 + 64,  (int)(w0.y * g0));
        atomicAdd(b0 + 128, (int)(w0.z * g0));
        atomicAdd(b0 + 192, (int)(w0.w * g0));
        if (lane == 0) atomicAdd(&hist[l0], 1);
    }
    __syncthreads();
    float* outp = part + (size_t)blockIdx.x * PART_F;
    for (int i = tid; i < 2 * SEG_F; i += 1024) outp[i] = (float)s[i] * INV_SUM;
    if (tid < K1) outp[2 * SEG_F + tid] = (float)hist[tid];
}

// ---- stage-1 reduce of partials: [nPart][PART_F] -> [NGRP][2*SEG_F] ----
__global__ __launch_bounds__(256) void kRed(const float* __restrict__ part, float* __restrict__ gred, int nPart)
{
    const int col = blockIdx.x * 256 + threadIdx.x;   // 0..8703 (34 blocks)
    const int g = blockIdx.y;
    const int per = nPart / NGRP;
    const float* p = part + (size_t)g * per * PART_F + col;
    float acc = 0.0f;
    for (int b = 0; b < per; ++b) acc += p[(size_t)b * PART_F];
    gred[g * (2 * SEG_F) + col] = acc;
}

// ---- stage-2: finish sums, normalize means; write mu in NATURAL layout ----
__global__ __launch_bounds__(256) void k_mu(float* __restrict__ ws, int nPart)
{
    const int k = blockIdx.x, t = threadIdx.x;
    __shared__ float C[256];
    float c = 0.0f;
    for (int b = t; b < nPart; b += 256) c += ws[PART_BASE + (size_t)b * PART_F + 2 * SEG_F + k];
    C[t] = c; __syncthreads();
    for (int s2 = 128; s2 > 0; s2 >>= 1) { if (t < s2) C[t] += C[t + s2]; __syncthreads(); }
    const float cnt = C[0];
    const float safe = fmaxf(cnt, 1.0f);
    float sd = 0.0f, sc = 0.0f;
    #pragma unroll
    for (int g = 0; g < NGRP; ++g) {
        sd += ws[GRED_BASE + g * 2 * SEG_F + k * 256 + t];
        sc += ws[GRED_BASE + g * 2 * SEG_F + SEG_F + k * 256 + t];
    }
    const float md = sd / safe, mc = sc / safe;
    __shared__ float A[256], B[256];
    A[t] = md * md; B[t] = mc * mc;
    __syncthreads();
    for (int s2 = 128; s2 > 0; s2 >>= 1) { if (t < s2) { A[t] += A[t + s2]; B[t] += B[t + s2]; } __syncthreads(); }
    const float id = 1.0f / fmaxf(sqrtf(A[0]), 1e-12f);
    const float ic = 1.0f / fmaxf(sqrtf(B[0]), 1e-12f);
    // de-permute: slot t holds element d = 4*(t%64) + t/64
    const int dnat = 4 * (t & 63) + (t >> 6);
    ws[MU_BASE + k * 256 + dnat]         = md * id;
    ws[MU_BASE + SEG_F + k * 256 + dnat] = mc * ic;
    if (t == 0) ws[GCNT_OFF + k] = cnt;
}

// ---- Pass 2: per-pixel losses -> fixed-point per-segment sums ----
__device__ __forceinline__ void row_part(const float4 v, const float4 w, int l, int lane,
                                         const float4* __restrict__ mud, const float4* __restrict__ muc,
                                         float& nd, float& nc, float& dd, float& dc)
{
    const float4 md = mud[l * 64 + lane];
    const float4 bd = mud[lane];
    const float4 mc = muc[l * 64 + lane];
    const float4 bc = muc[lane];
    nd = dot4s(v);
    nc = dot4s(w);
    // dd partial of (neg - pos) = v.(bg - mu_label); dc partial of (oth - pos) = w.(mu_label - bg)
    dd = v.x * (bd.x - md.x) + v.y * (bd.y - md.y) + v.z * (bd.z - md.z) + v.w * (bd.w - md.w);
    dc = w.x * (mc.x - bc.x) + w.y * (mc.y - bc.y) + w.z * (mc.z - bc.z) + w.w * (mc.w - bc.w);
}
__device__ __forceinline__ void row_commit(float nd, float nc, float dd, float dc, int l, int lane,
                                           int* __restrict__ lt, int* __restrict__ lc)
{
    float invd; asm("v_rsq_f32 %0, %1" : "=v"(invd) : "v"(nd));
    float invc; asm("v_rsq_f32 %0, %1" : "=v"(invc) : "v"(nc));
    const float xt = dd * invd * (1.0f / 0.07f);
    const float xc = dc * invc * (1.0f / 0.07f);
    const float plt = softplus_f(xt);
    const float plc = softplus_f(xc);
    if (lane == 0) {
        atomicAdd(&lt[l], (int)(plt * SCALE_L + 0.5f));   // softplus >= 0 -> trunc+0.5 = round
        atomicAdd(&lc[l], (int)(plc * SCALE_L + 0.5f));
    }
}

__global__ __launch_bounds__(512) void k_loss(const float4* __restrict__ dp, const float4* __restrict__ cf,
                                              const int* __restrict__ mask, float* __restrict__ ws,
                                              int nBlocks, int nRows)
{
    __shared__ float4 mud[SEG_F / 4], muc[SEG_F / 4];   // natural layout: mud[k*64+lane] = elems 4lane..4lane+3
    __shared__ int lt[K1], lc[K1];
    const int tid = threadIdx.x;
    const float4* musrc = (const float4*)(ws + MU_BASE);
    for (int i = tid; i < SEG_F / 4; i += 512) { mud[i] = musrc[i]; muc[i] = musrc[SEG_F / 4 + i]; }
    if (tid < K1) { lt[tid] = 0; lc[tid] = 0; }
    __syncthreads();

    const int lane = tid & 63;
    const int gw = blockIdx.x * 8 + (tid >> 6);
    const int S = nBlocks * 8;

    int r = gw;
    for (; r + S < nRows; r += 2 * S) {
        const int l0 = mask[r], l1 = mask[r + S];
        const float4 v0 = dp[(size_t)r * 64 + lane];
        const float4 w0 = cf[(size_t)r * 64 + lane];
        const float4 v1 = dp[(size_t)(r + S) * 64 + lane];
        const float4 w1 = cf[(size_t)(r + S) * 64 + lane];
        float nd0, nc0, dd0, dc0, nd1, nc1, dd1, dc1;
        row_part(v0, w0, l0, lane, mud, muc, nd0, nc0, dd0, dc0);
        row_part(v1, w1, l1, lane, mud, muc, nd1, nc1, dd1, dc1);
        nd0 = wave_sum(nd0); nc0 = wave_sum(nc0); dd0 = wave_sum(dd0); dc0 = wave_sum(dc0);
        nd1 = wave_sum(nd1); nc1 = wave_sum(nc1); dd1 = wave_sum(dd1); dc1 = wave_sum(dc1);
        row_commit(nd0, nc0, dd0, dc0, l0, lane, lt, lc);
        row_commit(nd1, nc1, dd1, dc1, l1, lane, lt, lc);
    }
    for (; r < nRows; r += S) {
        const int l0 = mask[r];
        const float4 v0 = dp[(size_t)r * 64 + lane];
        const float4 w0 = cf[(size_t)r * 64 + lane];
        float nd0, nc0, dd0, dc0;
        row_part(v0, w0, l0, lane, mud, muc, nd0, nc0, dd0, dc0);
        nd0 = wave_sum(nd0); nc0 = wave_sum(nc0); dd0 = wave_sum(dd0); dc0 = wave_sum(dc0);
        row_commit(nd0, nc0, dd0, dc0, l0, lane, lt, lc);
    }
    __syncthreads();
    if (tid < K1) {
        int* LT = (int*)ws + LT_OFF;
        int* LC = (int*)ws + LC_OFF;
        atomicAdd(&LT[tid], lt[tid]);
        atomicAdd(&LC[tid], lc[tid]);
    }
}

// ---- finalize scalar ----
__global__ void k_final(const float* __restrict__ ws, float* __restrict__ out)
{
    const int t = threadIdx.x; // 64
    const int* LT = (const int*)ws + LT_OFF;
    const int* LC = (const int*)ws + LC_OFF;
    float vt = 0.0f, vc = 0.0f, nv = 0.0f;
    if (t >= 1 && t < K1) {
        const float cnt = ws[GCNT_OFF + t];
        if (cnt >= 3.0f) {  // MIN_PIXELS
            const float safe = fmaxf(cnt, 1.0f);
            vt = (float)LT[t] * INV_L / safe;
            vc = (float)LC[t] * INV_L / safe;
            nv = 1.0f;
        }
    }
    #pragma unroll
    for (int o = 32; o > 0; o >>= 1) {
        vt += __shfl_xor(vt, o, 64);
        vc += __shfl_xor(vc, o, 64);
        nv += __shfl_xor(nv, o, 64);
    }
    if (t == 0) {
        const float n = fmaxf(nv, 1.0f);
        out[0] = vt / n + 0.5f * (vc / n);  // LAMBDA_CF = 0.5
    }
}

extern "C" void kernel_launch(void* const* d_in, const int* in_sizes, int n_in,
                              void* d_out, int out_size, void* d_ws, size_t ws_size,
                              hipStream_t stream)
{
    const float4* dp = (const float4*)d_in[0];
    const float4* cf = (const float4*)d_in[1];
    const int* mask  = (const int*)d_in[2];
    float* ws  = (float*)d_ws;
    float* out = (float*)d_out;
    const int nRows = in_sizes[2];

    long availF = (long)(ws_size / 4) - PART_BASE;
    int nPart = (int)(availF / PART_F);
    if (nPart > 512) nPart = 512;
    nPart &= ~7;            // multiple of NGRP
    if (nPart < 8) nPart = 8;

    hipMemsetAsync((void*)(ws + LT_OFF), 0, 2 * K1 * sizeof(int), stream);
    kA<<<nPart, 1024, 0, stream>>>(dp, cf, mask, ws + PART_BASE, nPart, nRows);
    kRed<<<dim3(34, NGRP), 256, 0, stream>>>(ws + PART_BASE, ws + GRED_BASE, nPart);
    k_mu<<<K1, 256, 0, stream>>>(ws, nPart);
    const int nB3 = 1024;
    k_loss<<<nB3, 512, 0, stream>>>(dp, cf, mask, ws, nB3, nRows);
    k_final<<<1, 64, 0, stream>>>(ws, out);
}